// Round 19
// baseline (226.685 us; speedup 1.0000x reference)
//
#include <hip/hip_runtime.h>
#include <hip/hip_fp16.h>
#include <math.h>

#define N_GRAPHS 256
#define F_IN 12
#define XS_STRIDE 16
#define HID 64
#define FC_DIM 140
#define SCAP 2304     // sorted+pad8 bucket stride; exact bucket count ~Poisson(1024)
#define NBK_MAX 1564  // max buckets+1 (N=100000 -> 1563 buckets)
#define NSRC 256      // phase-A blocks (= threads in phase-B gather)
#define EPB_MAX 6272  // per-source-block edge slice capacity (E=1.6M -> 6251)

typedef _Float16 h2v __attribute__((ext_vector_type(2)));

__device__ __forceinline__ float bcast_lane(float v, int k) {
    return __uint_as_float(__builtin_amdgcn_readlane(__float_as_uint(v), k));
}
__device__ __forceinline__ unsigned bcast_lane_u(unsigned v, int k) {
    return __builtin_amdgcn_readlane(v, k);
}

// ---------- phase A: block-local counting sort of a contiguous edge slice ----------
// ALL global writes coalesced (full lines) -> no scattered-store write amplification.
__global__ __launch_bounds__(1024) void count_bin(
        const int* __restrict__ src, const int* __restrict__ dst, int E, int epb, int nbk,
        int* __restrict__ eblk, int* __restrict__ hoff) {
    __shared__ int hc[NBK_MAX];    // histogram, then cursors
    __shared__ int hs[NBK_MAX];    // scanned offsets
    __shared__ int esl[EPB_MAX];   // block-locally sorted edges
    __shared__ int wsum[16];
    int k = blockIdx.x, tid = threadIdx.x;
    int base = k * epb;
    int cnt = min(epb, E - base); if (cnt < 0) cnt = 0;
    for (int j = tid; j < nbk; j += 1024) hc[j] = 0;
    __syncthreads();
    int pb[8], pv[8]; int np = 0;
    for (int i = tid; i < cnt; i += 1024) {
        int d = dst[base + i];
        int s = src[base + i];
        int b = d >> 6;
        atomicAdd(&hc[b], 1);
        pb[np] = b; pv[np] = s | ((d & 63) << 20); np++;
    }
    __syncthreads();
    // exclusive scan of hc[0..nbk-1] -> hs (VPT=2)
    int lane = tid & 63, wave = tid >> 6;
    int i0 = tid * 2;
    int v0 = (i0 < nbk) ? hc[i0] : 0;
    int v1 = (i0 + 1 < nbk) ? hc[i0 + 1] : 0;
    int s2 = v0 + v1;
    int incl = s2;
#pragma unroll
    for (int off = 1; off < 64; off <<= 1) {
        int t = __shfl_up(incl, off, 64);
        if (lane >= off) incl += t;
    }
    if (lane == 63) wsum[wave] = incl;
    __syncthreads();
    int woff = 0, tot = 0;
#pragma unroll
    for (int w = 0; w < 16; w++) { int xv = wsum[w]; tot += xv; if (w < wave) woff += xv; }
    int ex = woff + incl - s2;
    if (i0 < nbk) hs[i0] = ex;
    if (i0 + 1 < nbk) hs[i0 + 1] = ex + v0;
    if (tid == 0) hs[nbk] = tot;
    __syncthreads();
    for (int j = tid; j < nbk; j += 1024) hc[j] = hs[j];   // cursors
    __syncthreads();
    for (int q = 0; q < np; ++q) {
        int pos = atomicAdd(&hc[pb[q]], 1);
        esl[pos] = pv[q];
    }
    __syncthreads();
    for (int i = tid; i < cnt; i += 1024) eblk[k * EPB_MAX + i] = esl[i];       // coalesced
    for (int j = tid; j <= nbk; j += 1024) hoff[k * (nbk + 1) + j] = hs[j];     // coalesced
}

// ---------- phase B: per-bucket gather from 256 slices + counting sort + pad-8 + xs ----------
__global__ __launch_bounds__(256) void bucket_sort(
        const int* __restrict__ eblk, const int* __restrict__ hoff,
        const float* __restrict__ x,
        int* __restrict__ sedgeS, int* __restrict__ boff,
        float* __restrict__ dinv, __half* __restrict__ xs, int N, int nbk) {
    __shared__ int eslr[SCAP];
    __shared__ int esl[SCAP];
    __shared__ int cnt[64];
    __shared__ int cur[64];
    __shared__ int startl[64];
    __shared__ int pcl[64];
    __shared__ float dinvl[64];
    __shared__ int wsum4[4];
    int tid = threadIdx.x, b = blockIdx.x;
    if (b == 0 && tid == 0) {              // sentinel segment for agg_h paired chains
#pragma unroll
        for (int k = 0; k < 8; k++) sedgeS[(size_t)nbk * SCAP + k] = N;
    }
    int lane = tid & 63, wave = tid >> 6;
    int o0 = hoff[tid * (nbk + 1) + b];
    int o1 = hoff[tid * (nbk + 1) + b + 1];
    int ck = o1 - o0;
    int incl = ck;
#pragma unroll
    for (int off = 1; off < 64; off <<= 1) {
        int t = __shfl_up(incl, off, 64);
        if (lane >= off) incl += t;
    }
    if (lane == 63) wsum4[wave] = incl;
    __syncthreads();
    int woff = 0, ne = 0;
#pragma unroll
    for (int w = 0; w < 4; w++) { int xv = wsum4[w]; ne += xv; if (w < wave) woff += xv; }
    int gbase = woff + incl - ck;
    const int* seg = eblk + (size_t)tid * EPB_MAX;
    for (int i = 0; i < ck; ++i) {
        int p = gbase + i;
        if (p < SCAP) eslr[p] = seg[o0 + i];
    }
    if (ne > SCAP) ne = SCAP;
    __syncthreads();
    if (tid < 64) cnt[tid] = 0;
    __syncthreads();
    for (int idx = tid; idx < ne; idx += 256) atomicAdd(&cnt[(eslr[idx] >> 20) & 63], 1);
    __syncthreads();
    if (tid < 64) {
        int c = cnt[tid];
        int pc = (c + 7) & ~7;            // pad each node's segment to mult of 8
        int incl2 = pc;
#pragma unroll
        for (int off = 1; off < 64; off <<= 1) {
            int t = __shfl_up(incl2, off, 64);
            if (tid >= off) incl2 += t;
        }
        int st = incl2 - pc;
        startl[tid] = st; cur[tid] = st; pcl[tid] = pc;
        boff[b * 65 + tid] = st;
        if (tid == 63) boff[b * 65 + 64] = incl2;
        float di = rsqrtf((float)(c + 1));  // +1 self-loop (real degree)
        dinvl[tid] = di;
        int node = b * 64 + tid;
        if (node < N) dinv[node] = di;
    }
    __syncthreads();
    for (int idx = tid; idx < ne; idx += 256) {
        int v = eslr[idx];
        int pos = atomicAdd(&cur[(v >> 20) & 63], 1);
        esl[pos] = v & 0xFFFFF;           // src only; dlow implicit in position
    }
    __syncthreads();
    if (tid < 64) {                        // sentinel padding -> zero row N
        int end = startl[tid] + pcl[tid];
        for (int pos = cur[tid]; pos < end; ++pos) esl[pos] = N;
    }
    __syncthreads();
    int netot = startl[63] + pcl[63];
    for (int idx = tid; idx < netot; idx += 256) sedgeS[(size_t)b * SCAP + idx] = esl[idx];
    // fused make_xs for this bucket's nodes
    for (int idx = tid; idx < 64 * XS_STRIDE; idx += 256) {
        int nl = idx >> 4, f = idx & 15;
        int node = b * 64 + nl;
        if (node < N) {
            float v = (f < F_IN) ? dinvl[nl] * x[node * F_IN + f] : 0.f;
            xs[(size_t)node * XS_STRIDE + f] = __float2half(v);
        }
    }
}

// ---------- fused layer-1: 8-lane half2 gather, 16-deep, + mm1 + h1-pool ----------
__global__ __launch_bounds__(256) void agg_x_mm1(
        const __half2* __restrict__ xs2, const float* __restrict__ dinv,
        const int* __restrict__ boff, const int* __restrict__ sedgeS,
        const float* __restrict__ W1, const float* __restrict__ b1,
        const int* __restrict__ batch, float* __restrict__ pooled,
        __half* __restrict__ h1s, int N) {
    int tid = threadIdx.x, wv = tid >> 6, lane = tid & 63;
    int c = lane & 7, gb = lane & 56;  // group base within wave
    float w1c[F_IN];
#pragma unroll
    for (int k = 0; k < F_IN; k++) w1c[k] = W1[k * HID + lane];  // coalesced
    float bias = b1[lane];
    int node = blockIdx.x * 32 + (tid >> 3);
    float ax = 0.f, ay = 0.f, di = 0.f;
    if (node < N) {
        int b = node >> 6, dlow = node & 63;
        di = dinv[node];
        int p0 = boff[b * 65 + dlow], p1 = boff[b * 65 + dlow + 1];
        const int* ep = sedgeS + (size_t)b * SCAP;
        int base = p0;
        for (; base + 16 <= p1; base += 16) {   // 16 gathers in flight
            int ela = ep[base + c];
            int elb = ep[base + 8 + c];
            int ja[8], jb[8];
#pragma unroll
            for (int k = 0; k < 8; k++) ja[k] = __shfl(ela, gb + k, 64);
#pragma unroll
            for (int k = 0; k < 8; k++) jb[k] = __shfl(elb, gb + k, 64);
            float2 va[8], vb[8];
#pragma unroll
            for (int k = 0; k < 8; k++) va[k] = __half22float2(xs2[(size_t)ja[k] * 8 + c]);
#pragma unroll
            for (int k = 0; k < 8; k++) vb[k] = __half22float2(xs2[(size_t)jb[k] * 8 + c]);
#pragma unroll
            for (int k = 0; k < 8; k++) { ax += va[k].x + vb[k].x; ay += va[k].y + vb[k].y; }
        }
        if (base < p1) {                        // remainder: exactly 8 (pad-8)
            int el = ep[base + c];
            int j[8];
#pragma unroll
            for (int k = 0; k < 8; k++) j[k] = __shfl(el, gb + k, 64);
#pragma unroll
            for (int k = 0; k < 8; k++) {
                float2 v = __half22float2(xs2[(size_t)j[k] * 8 + c]);
                ax += v.x; ay += v.y;
            }
        }
        float2 sv = __half22float2(xs2[(size_t)node * 8 + c]);  // self-loop (prescaled)
        ax = di * (ax + sv.x);
        ay = di * (ay + sv.y);
    }
    // epilogue: 8 nodes of this wave; feature k of node q lives in lane q*8+(k>>1)
    int nb0 = blockIdx.x * 32 + wv * 8;
    int curg = -1; float pacc = 0.f;
    for (int q = 0; q < 8; ++q) {
        int nq = nb0 + q;
        if (nq >= N) break;
        float o = bias;
#pragma unroll
        for (int k = 0; k < F_IN; k++) {
            float r = (k & 1) ? bcast_lane(ay, q * 8 + (k >> 1))
                              : bcast_lane(ax, q * 8 + (k >> 1));
            o += r * w1c[k];
        }
        float v = tanhf(o);
        float dq = bcast_lane(di, q * 8);
        h1s[(size_t)nq * HID + lane] = __float2half(dq * v);
        int g = batch[nq];
        if (g != curg) {
            if (curg >= 0) atomicAdd(&pooled[curg * FC_DIM + F_IN + lane], pacc);
            pacc = 0.f; curg = g;
        }
        pacc += v;
    }
    if (curg >= 0) atomicAdd(&pooled[curg * FC_DIM + F_IN + lane], pacc);
}

// ---------- fused layer-2: paired half2 gathers (2 edges/instr) + dot2 mm2 + pool ----------
// Wave gathers node-A rows in lanes 0..31 and node-B rows in lanes 32..63 as half2:
// one 128B coalesced read serves TWO edges. Lane c holds feature pair {2c,2c+1} --
// exactly the packed operand fdot2 needs (no bpermute). Block = bucket (64 nodes).
__global__ __launch_bounds__(256) void agg_h_mm2(
        const __half* __restrict__ h1s, const float* __restrict__ dinv,
        const int* __restrict__ boff, const int* __restrict__ sedgeS,
        const float* __restrict__ W2, const float* __restrict__ b2,
        const int* __restrict__ batch, float* __restrict__ pooled, int N, int nbk) {
    int tid = threadIdx.x, wv = tid >> 6, lane = tid & 63;
    int half = lane >> 5, c = lane & 31;
    const __half2* h1s2 = (const __half2*)h1s;
    h2v wpk[32];   // W2 column `lane`, packed pairs (32 VGPRs)
#pragma unroll
    for (int k2 = 0; k2 < 32; k2++) {
        h2v w; w[0] = (_Float16)W2[(2 * k2) * HID + lane];
        w[1] = (_Float16)W2[(2 * k2 + 1) * HID + lane];
        wpk[k2] = w;
    }
    float bias = b2[lane];
    int b = blockIdx.x;
    const int* ep = sedgeS + (size_t)b * SCAP;
    const int sent = (nbk - b) * SCAP;     // 8-int sentinel segment (value N) past last bucket
    int curg = -1; float pacc = 0.f;
    for (int rq = 0; rq < 2; ++rq) {
        int dl0 = wv * 16 + rq * 8;
        int n0 = b * 64 + dl0;
        if (n0 >= N) break;
        int bnd[9];
#pragma unroll
        for (int t = 0; t < 9; t++) bnd[t] = boff[b * 65 + dl0 + t];
        int iiA[4], iiB[4]; float ax[4], ay[4];
#pragma unroll
        for (int s = 0; s < 4; s++) {
            iiA[s] = bnd[2 * s]; iiB[s] = bnd[2 * s + 1];
            ax[s] = 0.f; ay[s] = 0.f;
        }
        for (;;) {
            bool any = false;
#pragma unroll
            for (int s = 0; s < 4; s++)
                any |= (iiA[s] < bnd[2 * s + 1]) | (iiB[s] < bnd[2 * s + 2]);
            if (!any) break;
#pragma unroll
            for (int s = 0; s < 4; s++) {
                bool actA = iiA[s] < bnd[2 * s + 1];
                bool actB = iiB[s] < bnd[2 * s + 2];
                if (!(actA | actB)) continue;
                int ba = actA ? iiA[s] : sent;   // scalar select of segment base
                int bb = actB ? iiB[s] : sent;
                int jj[8];
#pragma unroll
                for (int k = 0; k < 8; k++) {
                    int ja = ep[ba + k];          // uniform -> s_load
                    int jb = ep[bb + k];
                    jj[k] = half ? jb : ja;       // v_cndmask
                }
                __half2 hv[8];
#pragma unroll
                for (int k = 0; k < 8; k++) hv[k] = h1s2[(size_t)jj[k] * 32 + c];
#pragma unroll
                for (int k = 0; k < 8; k++) {
                    float2 v = __half22float2(hv[k]);
                    ax[s] += v.x; ay[s] += v.y;
                }
                if (actA) iiA[s] += 8;
                if (actB) iiB[s] += 8;
            }
        }
#pragma unroll
        for (int s = 0; s < 4; ++s) {
            int nu = n0 + 2 * s + half;           // per-lane node id (A or B by half)
            int nsr = min(nu, N);                 // row N = zeros
            float di = dinv[min(nu, N - 1)];
            float2 sv = __half22float2(h1s2[(size_t)nsr * 32 + c]);  // self-loop
            float rx = di * (ax[s] + sv.x);
            float ry = di * (ay[s] + sv.y);
            unsigned pk = (unsigned)__half_as_ushort(__float2half(rx))
                        | ((unsigned)__half_as_ushort(__float2half(ry)) << 16);
#pragma unroll
            for (int hh = 0; hh < 2; ++hh) {
                int node = n0 + 2 * s + hh;
                if (node >= N) break;
                float o = bias;
#if __has_builtin(__builtin_amdgcn_fdot2)
#pragma unroll
                for (int k2 = 0; k2 < 32; ++k2) {
                    unsigned pr = bcast_lane_u(pk, hh * 32 + k2);
                    o = __builtin_amdgcn_fdot2(__builtin_bit_cast(h2v, pr), wpk[k2], o, false);
                }
#else
#pragma unroll
                for (int k2 = 0; k2 < 32; ++k2) {
                    unsigned pr = bcast_lane_u(pk, hh * 32 + k2);
                    float vx = __half2float(__ushort_as_half((unsigned short)(pr & 0xFFFF)));
                    float vy = __half2float(__ushort_as_half((unsigned short)(pr >> 16)));
                    o += vx * (float)wpk[k2][0] + vy * (float)wpk[k2][1];
                }
#endif
                float val = tanhf(o);
                int g = batch[node];
                if (g != curg) {
                    if (curg >= 0) atomicAdd(&pooled[curg * FC_DIM + F_IN + HID + lane], pacc);
                    pacc = 0.f; curg = g;
                }
                pacc += val;
            }
        }
    }
    if (curg >= 0) atomicAdd(&pooled[curg * FC_DIM + F_IN + HID + lane], pacc);
}

// ---------- fc: fused x-pool (graph-local, coalesced) + matvec ----------
__device__ __forceinline__ int lower_bound_i(const int* b, int n, int v) {
    int lo = 0, hi = n;
    while (lo < hi) { int m = (lo + hi) >> 1; if (b[m] < v) lo = m + 1; else hi = m; }
    return lo;
}

__global__ __launch_bounds__(192) void fc_kernel(
        const float* __restrict__ x, const int* __restrict__ batch,
        const float* __restrict__ pooled, const float* __restrict__ fcW,
        const float* __restrict__ fcb, float* __restrict__ out, int N) {
    __shared__ float p[FC_DIM];
    int g = blockIdx.x, tid = threadIdx.x;
    if (tid < FC_DIM) p[tid] = (tid < F_IN) ? 0.f : pooled[g * FC_DIM + tid];
    __syncthreads();
    int start = lower_bound_i(batch, N, g);
    int end = lower_bound_i(batch, N, g + 1);
    int base = start * F_IN;
    int cnt = (end - start) * F_IN;
    float acc = 0.f;
    for (int i = tid; i < cnt; i += 192) acc += x[base + i];  // stride 192 = 16*12
    atomicAdd(&p[tid % F_IN], acc);
    __syncthreads();
    if (tid < FC_DIM) {
        float o = fcb[tid];
        for (int k = 0; k < FC_DIM; k++) o += p[k] * fcW[tid * FC_DIM + k];
        out[g * FC_DIM + tid] = o;
    }
}

extern "C" void kernel_launch(void* const* d_in, const int* in_sizes, int n_in,
                              void* d_out, int out_size, void* d_ws, size_t ws_size,
                              hipStream_t stream) {
    const float* x   = (const float*)d_in[0];
    const float* W1  = (const float*)d_in[1];
    const float* b1  = (const float*)d_in[2];
    const float* W2  = (const float*)d_in[3];
    const float* b2  = (const float*)d_in[4];
    const float* fcW = (const float*)d_in[5];
    const float* fcb = (const float*)d_in[6];
    const int*   ei  = (const int*)d_in[7];
    const int*   batch = (const int*)d_in[8];
    const int N = in_sizes[8];
    const int E = in_sizes[7] / 2;
    const int* src = ei;
    const int* dst = ei + E;
    const int NB = (N + 63) / 64;          // 1563 buckets (NBK_MAX-1)
    const int epb = (E + NSRC - 1) / NSRC; // 6250 <= EPB_MAX

    char* ws = (char*)d_ws;
    size_t off = 0;
    auto alloc = [&](size_t bytes) -> void* {
        void* p = ws + off; off += (bytes + 255) & ~(size_t)255; return p;
    };
    int*    eblk   = (int*)alloc((size_t)NSRC * EPB_MAX * 4);    // block-sorted slices
    int*    hoff   = (int*)alloc((size_t)NSRC * (NB + 1) * 4);   // per-slice bucket offsets
    int*    sedgeS = (int*)alloc(((size_t)NB * SCAP + 64) * 4);  // sorted+padded + sentinel seg
    int*    boff   = (int*)alloc((size_t)NB * 65 * 4);
    float*  dinv   = (float*)alloc((size_t)N * 4);
    __half* xs     = (__half*)alloc(((size_t)N + 1) * XS_STRIDE * 2);  // +1 zero row
    __half* h1s    = (__half*)alloc(((size_t)N + 1) * HID * 2);        // +1 zero row
    float*  pooled = (float*)alloc((size_t)N_GRAPHS * FC_DIM * 4);
    float* out = (float*)d_out;

    hipMemsetAsync(pooled, 0, (size_t)N_GRAPHS * FC_DIM * 4, stream);
    hipMemsetAsync(xs + (size_t)N * XS_STRIDE, 0, XS_STRIDE * 2, stream);   // sentinel row
    hipMemsetAsync(h1s + (size_t)N * HID, 0, HID * 2, stream);              // sentinel row

    count_bin<<<NSRC, 1024, 0, stream>>>(src, dst, E, epb, NB, eblk, hoff);
    bucket_sort<<<NB, 256, 0, stream>>>(eblk, hoff, x, sedgeS, boff, dinv, xs, N, NB);
    agg_x_mm1<<<(N + 31) / 32, 256, 0, stream>>>((const __half2*)xs, dinv, boff, sedgeS,
                                                 W1, b1, batch, pooled, h1s, N);
    agg_h_mm2<<<NB, 256, 0, stream>>>(h1s, dinv, boff, sedgeS,
                                      W2, b2, batch, pooled, N, NB);
    fc_kernel<<<N_GRAPHS, 192, 0, stream>>>(x, batch, pooled, fcW, fcb, out, N);
}

// Round 20
// 214.963 us; speedup vs baseline: 1.0545x; 1.0545x over previous
//
#include <hip/hip_runtime.h>
#include <hip/hip_fp16.h>
#include <math.h>

#define N_GRAPHS 256
#define F_IN 12
#define XS_STRIDE 16
#define HID 64
#define FC_DIM 140
#define SCAP 2304     // sorted+pad8 bucket stride; exact bucket count ~Poisson(1024)
#define NBK_MAX 1564  // max buckets+1 (N=100000 -> 1563 buckets)
#define NSRC 256      // phase-A blocks (= threads in phase-B gather)
#define EPB_MAX 6272  // per-source-block edge slice capacity (E=1.6M -> 6251)

typedef _Float16 h2v __attribute__((ext_vector_type(2)));

__device__ __forceinline__ float bcast_lane(float v, int k) {
    return __uint_as_float(__builtin_amdgcn_readlane(__float_as_uint(v), k));
}
__device__ __forceinline__ unsigned bcast_lane_u(unsigned v, int k) {
    return __builtin_amdgcn_readlane(v, k);
}

// ---------- phase A: block-local counting sort of a contiguous edge slice ----------
// ALL global writes coalesced (full lines) -> no scattered-store write amplification.
__global__ __launch_bounds__(1024) void count_bin(
        const int* __restrict__ src, const int* __restrict__ dst, int E, int epb, int nbk,
        int* __restrict__ eblk, int* __restrict__ hoff) {
    __shared__ int hc[NBK_MAX];    // histogram, then cursors
    __shared__ int hs[NBK_MAX];    // scanned offsets
    __shared__ int esl[EPB_MAX];   // block-locally sorted edges
    __shared__ int wsum[16];
    int k = blockIdx.x, tid = threadIdx.x;
    int base = k * epb;
    int cnt = min(epb, E - base); if (cnt < 0) cnt = 0;
    for (int j = tid; j < nbk; j += 1024) hc[j] = 0;
    __syncthreads();
    int pb[8], pv[8]; int np = 0;
    for (int i = tid; i < cnt; i += 1024) {
        int d = dst[base + i];
        int s = src[base + i];
        int b = d >> 6;
        atomicAdd(&hc[b], 1);
        pb[np] = b; pv[np] = s | ((d & 63) << 20); np++;
    }
    __syncthreads();
    // exclusive scan of hc[0..nbk-1] -> hs (VPT=2)
    int lane = tid & 63, wave = tid >> 6;
    int i0 = tid * 2;
    int v0 = (i0 < nbk) ? hc[i0] : 0;
    int v1 = (i0 + 1 < nbk) ? hc[i0 + 1] : 0;
    int s2 = v0 + v1;
    int incl = s2;
#pragma unroll
    for (int off = 1; off < 64; off <<= 1) {
        int t = __shfl_up(incl, off, 64);
        if (lane >= off) incl += t;
    }
    if (lane == 63) wsum[wave] = incl;
    __syncthreads();
    int woff = 0, tot = 0;
#pragma unroll
    for (int w = 0; w < 16; w++) { int xv = wsum[w]; tot += xv; if (w < wave) woff += xv; }
    int ex = woff + incl - s2;
    if (i0 < nbk) hs[i0] = ex;
    if (i0 + 1 < nbk) hs[i0 + 1] = ex + v0;
    if (tid == 0) hs[nbk] = tot;
    __syncthreads();
    for (int j = tid; j < nbk; j += 1024) hc[j] = hs[j];   // cursors
    __syncthreads();
    for (int q = 0; q < np; ++q) {
        int pos = atomicAdd(&hc[pb[q]], 1);
        esl[pos] = pv[q];
    }
    __syncthreads();
    for (int i = tid; i < cnt; i += 1024) eblk[k * EPB_MAX + i] = esl[i];       // coalesced
    for (int j = tid; j <= nbk; j += 1024) hoff[k * (nbk + 1) + j] = hs[j];     // coalesced
}

// ---------- phase B: per-bucket gather from 256 slices + counting sort + pad-8 + xs ----------
__global__ __launch_bounds__(256) void bucket_sort(
        const int* __restrict__ eblk, const int* __restrict__ hoff,
        const float* __restrict__ x,
        int* __restrict__ sedgeS, int* __restrict__ boff,
        float* __restrict__ dinv, __half* __restrict__ xs, int N, int nbk) {
    __shared__ int eslr[SCAP];
    __shared__ int esl[SCAP];
    __shared__ int cnt[64];
    __shared__ int cur[64];
    __shared__ int startl[64];
    __shared__ int pcl[64];
    __shared__ float dinvl[64];
    __shared__ int wsum4[4];
    int tid = threadIdx.x, b = blockIdx.x;
    int lane = tid & 63, wave = tid >> 6;
    int o0 = hoff[tid * (nbk + 1) + b];
    int o1 = hoff[tid * (nbk + 1) + b + 1];
    int ck = o1 - o0;
    int incl = ck;
#pragma unroll
    for (int off = 1; off < 64; off <<= 1) {
        int t = __shfl_up(incl, off, 64);
        if (lane >= off) incl += t;
    }
    if (lane == 63) wsum4[wave] = incl;
    __syncthreads();
    int woff = 0, ne = 0;
#pragma unroll
    for (int w = 0; w < 4; w++) { int xv = wsum4[w]; ne += xv; if (w < wave) woff += xv; }
    int gbase = woff + incl - ck;
    const int* seg = eblk + (size_t)tid * EPB_MAX;
    for (int i = 0; i < ck; ++i) {
        int p = gbase + i;
        if (p < SCAP) eslr[p] = seg[o0 + i];
    }
    if (ne > SCAP) ne = SCAP;
    __syncthreads();
    if (tid < 64) cnt[tid] = 0;
    __syncthreads();
    for (int idx = tid; idx < ne; idx += 256) atomicAdd(&cnt[(eslr[idx] >> 20) & 63], 1);
    __syncthreads();
    if (tid < 64) {
        int c = cnt[tid];
        int pc = (c + 7) & ~7;            // pad each node's segment to mult of 8
        int incl2 = pc;
#pragma unroll
        for (int off = 1; off < 64; off <<= 1) {
            int t = __shfl_up(incl2, off, 64);
            if (tid >= off) incl2 += t;
        }
        int st = incl2 - pc;
        startl[tid] = st; cur[tid] = st; pcl[tid] = pc;
        boff[b * 65 + tid] = st;
        if (tid == 63) boff[b * 65 + 64] = incl2;
        float di = rsqrtf((float)(c + 1));  // +1 self-loop (real degree)
        dinvl[tid] = di;
        int node = b * 64 + tid;
        if (node < N) dinv[node] = di;
    }
    __syncthreads();
    for (int idx = tid; idx < ne; idx += 256) {
        int v = eslr[idx];
        int pos = atomicAdd(&cur[(v >> 20) & 63], 1);
        esl[pos] = v & 0xFFFFF;           // src only; dlow implicit in position
    }
    __syncthreads();
    if (tid < 64) {                        // sentinel padding -> zero row N
        int end = startl[tid] + pcl[tid];
        for (int pos = cur[tid]; pos < end; ++pos) esl[pos] = N;
    }
    __syncthreads();
    int netot = startl[63] + pcl[63];
    for (int idx = tid; idx < netot; idx += 256) sedgeS[(size_t)b * SCAP + idx] = esl[idx];
    // fused make_xs for this bucket's nodes
    for (int idx = tid; idx < 64 * XS_STRIDE; idx += 256) {
        int nl = idx >> 4, f = idx & 15;
        int node = b * 64 + nl;
        if (node < N) {
            float v = (f < F_IN) ? dinvl[nl] * x[node * F_IN + f] : 0.f;
            xs[(size_t)node * XS_STRIDE + f] = __float2half(v);
        }
    }
}

// ---------- fused layer-1: 8-lane half2 gather, 16-deep, + mm1 + h1-pool ----------
__global__ __launch_bounds__(256) void agg_x_mm1(
        const __half2* __restrict__ xs2, const float* __restrict__ dinv,
        const int* __restrict__ boff, const int* __restrict__ sedgeS,
        const float* __restrict__ W1, const float* __restrict__ b1,
        const int* __restrict__ batch, float* __restrict__ pooled,
        __half* __restrict__ h1s, int N) {
    int tid = threadIdx.x, wv = tid >> 6, lane = tid & 63;
    int c = lane & 7, gb = lane & 56;  // group base within wave
    float w1c[F_IN];
#pragma unroll
    for (int k = 0; k < F_IN; k++) w1c[k] = W1[k * HID + lane];  // coalesced
    float bias = b1[lane];
    int node = blockIdx.x * 32 + (tid >> 3);
    float ax = 0.f, ay = 0.f, di = 0.f;
    if (node < N) {
        int b = node >> 6, dlow = node & 63;
        di = dinv[node];
        int p0 = boff[b * 65 + dlow], p1 = boff[b * 65 + dlow + 1];
        const int* ep = sedgeS + (size_t)b * SCAP;
        int base = p0;
        for (; base + 16 <= p1; base += 16) {   // 16 gathers in flight
            int ela = ep[base + c];
            int elb = ep[base + 8 + c];
            int ja[8], jb[8];
#pragma unroll
            for (int k = 0; k < 8; k++) ja[k] = __shfl(ela, gb + k, 64);
#pragma unroll
            for (int k = 0; k < 8; k++) jb[k] = __shfl(elb, gb + k, 64);
            float2 va[8], vb[8];
#pragma unroll
            for (int k = 0; k < 8; k++) va[k] = __half22float2(xs2[(size_t)ja[k] * 8 + c]);
#pragma unroll
            for (int k = 0; k < 8; k++) vb[k] = __half22float2(xs2[(size_t)jb[k] * 8 + c]);
#pragma unroll
            for (int k = 0; k < 8; k++) { ax += va[k].x + vb[k].x; ay += va[k].y + vb[k].y; }
        }
        if (base < p1) {                        // remainder: exactly 8 (pad-8)
            int el = ep[base + c];
            int j[8];
#pragma unroll
            for (int k = 0; k < 8; k++) j[k] = __shfl(el, gb + k, 64);
#pragma unroll
            for (int k = 0; k < 8; k++) {
                float2 v = __half22float2(xs2[(size_t)j[k] * 8 + c]);
                ax += v.x; ay += v.y;
            }
        }
        float2 sv = __half22float2(xs2[(size_t)node * 8 + c]);  // self-loop (prescaled)
        ax = di * (ax + sv.x);
        ay = di * (ay + sv.y);
    }
    // epilogue: 8 nodes of this wave; feature k of node q lives in lane q*8+(k>>1)
    int nb0 = blockIdx.x * 32 + wv * 8;
    int curg = -1; float pacc = 0.f;
    for (int q = 0; q < 8; ++q) {
        int nq = nb0 + q;
        if (nq >= N) break;
        float o = bias;
#pragma unroll
        for (int k = 0; k < F_IN; k++) {
            float r = (k & 1) ? bcast_lane(ay, q * 8 + (k >> 1))
                              : bcast_lane(ax, q * 8 + (k >> 1));
            o += r * w1c[k];
        }
        float v = tanhf(o);
        float dq = bcast_lane(di, q * 8);
        h1s[(size_t)nq * HID + lane] = __float2half(dq * v);
        int g = batch[nq];
        if (g != curg) {
            if (curg >= 0) atomicAdd(&pooled[curg * FC_DIM + F_IN + lane], pacc);
            pacc = 0.f; curg = g;
        }
        pacc += v;
    }
    if (curg >= 0) atomicAdd(&pooled[curg * FC_DIM + F_IN + lane], pacc);
}

// ---------- fused layer-2: 2 rounds x 4-chain interleaved walk + dot2 mm2 + pool ----------
// NPB=32: W2 register-pack (64 coalesced loads/wave) amortized over 8 nodes, not 4.
#define NPB 32   // nodes per block (8 per wave: two 4-chain rounds)
__global__ __launch_bounds__(256) void agg_h_mm2(
        const __half* __restrict__ h1s, const float* __restrict__ dinv,
        const int* __restrict__ boff, const int* __restrict__ sedgeS,
        const float* __restrict__ W2, const float* __restrict__ b2,
        const int* __restrict__ batch, float* __restrict__ pooled, int N) {
    int tid = threadIdx.x, wv = tid >> 6, lane = tid & 63;
    h2v wpk[32];   // W2 column `lane`, packed pairs (32 VGPRs)
#pragma unroll
    for (int k2 = 0; k2 < 32; k2++) {
        h2v w; w[0] = (_Float16)W2[(2 * k2) * HID + lane];
        w[1] = (_Float16)W2[(2 * k2 + 1) * HID + lane];
        wpk[k2] = w;
    }
    float bias = b2[lane];
    int curg = -1; float pacc = 0.f;
    for (int rq = 0; rq < 2; ++rq) {
        int node0 = blockIdx.x * NPB + wv * 8 + rq * 4;
        if (node0 >= N) break;
        int n0 = __builtin_amdgcn_readfirstlane(node0);
        int bu = n0 >> 6, dl0 = n0 & 63;   // 4-aligned chunk never straddles a bucket
        const int* ep = sedgeS + (size_t)bu * SCAP;
        int bnd[5];
#pragma unroll
        for (int t = 0; t < 5; t++) bnd[t] = boff[bu * 65 + dl0 + t];
        int ii[4]; float acc[4];
#pragma unroll
        for (int s = 0; s < 4; s++) { ii[s] = bnd[s]; acc[s] = 0.f; }
        for (;;) {
            bool a0 = ii[0] < bnd[1], a1 = ii[1] < bnd[2], a2 = ii[2] < bnd[3], a3 = ii[3] < bnd[4];
            if (!(a0 | a1 | a2 | a3)) break;
            __half hv[4][8];
#pragma unroll
            for (int s = 0; s < 4; s++) {
                bool act = (s == 0) ? a0 : (s == 1) ? a1 : (s == 2) ? a2 : a3;
                if (act) {
                    int j[8];
#pragma unroll
                    for (int k = 0; k < 8; k++) j[k] = ep[ii[s] + k];   // uniform -> s_load
#pragma unroll
                    for (int k = 0; k < 8; k++) hv[s][k] = h1s[(size_t)j[k] * HID + lane];
                }
            }
#pragma unroll
            for (int s = 0; s < 4; s++) {
                bool act = (s == 0) ? a0 : (s == 1) ? a1 : (s == 2) ? a2 : a3;
                if (act) {
                    float t0 = __half2float(hv[s][0]) + __half2float(hv[s][1]);
                    float t1 = __half2float(hv[s][2]) + __half2float(hv[s][3]);
                    float t2 = __half2float(hv[s][4]) + __half2float(hv[s][5]);
                    float t3 = __half2float(hv[s][6]) + __half2float(hv[s][7]);
                    acc[s] += (t0 + t1) + (t2 + t3);
                    ii[s] += 8;
                }
            }
        }
#pragma unroll
        for (int s = 0; s < 4; ++s) {
            int nu = n0 + s;
            if (nu >= N) break;
            float di = dinv[nu];
            float a = acc[s] + __half2float(h1s[(size_t)nu * HID + lane]);  // self-loop
            float r = di * a;                     // lane f holds agg[f]
            // pack r (fp16) pairs: lane k (k<32) gets {r[2k], r[2k+1]}
            unsigned rhu = (unsigned)__half_as_ushort(__float2half(r));
            unsigned lo = (unsigned)__builtin_amdgcn_ds_bpermute(lane * 8, (int)rhu);
            unsigned hi = (unsigned)__builtin_amdgcn_ds_bpermute(lane * 8 + 4, (int)rhu);
            unsigned pk = (lo & 0xFFFFu) | (hi << 16);
            float o = bias;
#if __has_builtin(__builtin_amdgcn_fdot2)
#pragma unroll
            for (int k2 = 0; k2 < 32; ++k2) {
                unsigned pr = bcast_lane_u(pk, k2);
                o = __builtin_amdgcn_fdot2(__builtin_bit_cast(h2v, pr), wpk[k2], o, false);
            }
#else
#pragma unroll
            for (int k2 = 0; k2 < 32; ++k2) {
                unsigned pr = bcast_lane_u(pk, k2);
                float rx = __half2float(__ushort_as_half((unsigned short)(pr & 0xFFFF)));
                float ry = __half2float(__ushort_as_half((unsigned short)(pr >> 16)));
                o += rx * (float)wpk[k2][0] + ry * (float)wpk[k2][1];
            }
#endif
            float val = tanhf(o);
            int g = batch[nu];
            if (g != curg) {
                if (curg >= 0) atomicAdd(&pooled[curg * FC_DIM + F_IN + HID + lane], pacc);
                pacc = 0.f; curg = g;
            }
            pacc += val;
        }
    }
    if (curg >= 0) atomicAdd(&pooled[curg * FC_DIM + F_IN + HID + lane], pacc);
}

// ---------- fc: fused x-pool (graph-local, coalesced) + matvec ----------
__device__ __forceinline__ int lower_bound_i(const int* b, int n, int v) {
    int lo = 0, hi = n;
    while (lo < hi) { int m = (lo + hi) >> 1; if (b[m] < v) lo = m + 1; else hi = m; }
    return lo;
}

__global__ __launch_bounds__(192) void fc_kernel(
        const float* __restrict__ x, const int* __restrict__ batch,
        const float* __restrict__ pooled, const float* __restrict__ fcW,
        const float* __restrict__ fcb, float* __restrict__ out, int N) {
    __shared__ float p[FC_DIM];
    int g = blockIdx.x, tid = threadIdx.x;
    if (tid < FC_DIM) p[tid] = (tid < F_IN) ? 0.f : pooled[g * FC_DIM + tid];
    __syncthreads();
    int start = lower_bound_i(batch, N, g);
    int end = lower_bound_i(batch, N, g + 1);
    int base = start * F_IN;
    int cnt = (end - start) * F_IN;
    float acc = 0.f;
    for (int i = tid; i < cnt; i += 192) acc += x[base + i];  // stride 192 = 16*12
    atomicAdd(&p[tid % F_IN], acc);
    __syncthreads();
    if (tid < FC_DIM) {
        float o = fcb[tid];
        for (int k = 0; k < FC_DIM; k++) o += p[k] * fcW[tid * FC_DIM + k];
        out[g * FC_DIM + tid] = o;
    }
}

extern "C" void kernel_launch(void* const* d_in, const int* in_sizes, int n_in,
                              void* d_out, int out_size, void* d_ws, size_t ws_size,
                              hipStream_t stream) {
    const float* x   = (const float*)d_in[0];
    const float* W1  = (const float*)d_in[1];
    const float* b1  = (const float*)d_in[2];
    const float* W2  = (const float*)d_in[3];
    const float* b2  = (const float*)d_in[4];
    const float* fcW = (const float*)d_in[5];
    const float* fcb = (const float*)d_in[6];
    const int*   ei  = (const int*)d_in[7];
    const int*   batch = (const int*)d_in[8];
    const int N = in_sizes[8];
    const int E = in_sizes[7] / 2;
    const int* src = ei;
    const int* dst = ei + E;
    const int NB = (N + 63) / 64;          // 1563 buckets (NBK_MAX-1)
    const int epb = (E + NSRC - 1) / NSRC; // 6250 <= EPB_MAX

    char* ws = (char*)d_ws;
    size_t off = 0;
    auto alloc = [&](size_t bytes) -> void* {
        void* p = ws + off; off += (bytes + 255) & ~(size_t)255; return p;
    };
    int*    eblk   = (int*)alloc((size_t)NSRC * EPB_MAX * 4);    // block-sorted slices
    int*    hoff   = (int*)alloc((size_t)NSRC * (NB + 1) * 4);   // per-slice bucket offsets
    int*    sedgeS = (int*)alloc((size_t)NB * SCAP * 4);         // sorted+padded buckets
    int*    boff   = (int*)alloc((size_t)NB * 65 * 4);
    float*  dinv   = (float*)alloc((size_t)N * 4);
    __half* xs     = (__half*)alloc(((size_t)N + 1) * XS_STRIDE * 2);  // +1 zero row
    __half* h1s    = (__half*)alloc(((size_t)N + 1) * HID * 2);        // +1 zero row
    float*  pooled = (float*)alloc((size_t)N_GRAPHS * FC_DIM * 4);
    float* out = (float*)d_out;

    hipMemsetAsync(pooled, 0, (size_t)N_GRAPHS * FC_DIM * 4, stream);
    hipMemsetAsync(xs + (size_t)N * XS_STRIDE, 0, XS_STRIDE * 2, stream);   // sentinel row
    hipMemsetAsync(h1s + (size_t)N * HID, 0, HID * 2, stream);              // sentinel row

    count_bin<<<NSRC, 1024, 0, stream>>>(src, dst, E, epb, NB, eblk, hoff);
    bucket_sort<<<NB, 256, 0, stream>>>(eblk, hoff, x, sedgeS, boff, dinv, xs, N, NB);
    agg_x_mm1<<<(N + 31) / 32, 256, 0, stream>>>((const __half2*)xs, dinv, boff, sedgeS,
                                                 W1, b1, batch, pooled, h1s, N);
    agg_h_mm2<<<(N + NPB - 1) / NPB, 256, 0, stream>>>(h1s, dinv, boff, sedgeS,
                                                       W2, b2, batch, pooled, N);
    fc_kernel<<<N_GRAPHS, 192, 0, stream>>>(x, batch, pooled, fcW, fcb, out, N);
}